// Round 1
// baseline (114.000 us; speedup 1.0000x reference)
//
#include <hip/hip_runtime.h>
#include <cmath>
#include <cstdint>

typedef __attribute__((ext_vector_type(8))) short short8;
typedef __attribute__((ext_vector_type(4))) float f32x4;

struct Lams { float v[8]; };

#define NC 8
#define NB 4
#define NT 8192
#define ND 64
#define CL 128               // chunk length (rows per block)
#define NK (NT / CL)         // 64 chunks per (dir,c,b)

// f32 -> bf16 round-to-nearest-even
__device__ __forceinline__ short f2bf(float f) {
    uint32_t u = __builtin_bit_cast(uint32_t, f);
    u += 0x7FFFu + ((u >> 16) & 1u);
    return (short)(u >> 16);
}

__device__ __forceinline__ short8 cvt8(f32x4 a, f32x4 b) {
    short8 r;
    r[0]=f2bf(a[0]); r[1]=f2bf(a[1]); r[2]=f2bf(a[2]); r[3]=f2bf(a[3]);
    r[4]=f2bf(b[0]); r[5]=f2bf(b[1]); r[6]=f2bf(b[2]); r[7]=f2bf(b[3]);
    return r;
}

// K1: gated compute (MFMA) + chunk-local scan; writes local scan to out,
// chunk-end vector to ws. Everything in "scan coordinates" tr (tr = t for
// fwd, tr = NT-1-t for bwd); only global row index flips with dir.
__global__ __launch_bounds__(256) void k1_local(
    const float* __restrict__ x, const float* __restrict__ Wf,
    const float* __restrict__ bf, const float* __restrict__ Wb,
    const float* __restrict__ bb, float* __restrict__ out,
    float* __restrict__ ws, Lams lams)
{
    __shared__ float buf[CL][ND];       // 32 KiB gated / scanned values
    __shared__ float ends_lds[4][ND];   // per-wave sub-chunk ends

    const int tid  = threadIdx.x;
    const int lane = tid & 63;
    const int w    = tid >> 6;          // wave 0..3

    int idx = blockIdx.x;
    const int k   = idx & (NK - 1); idx >>= 6;
    const int b   = idx & (NB - 1); idx >>= 2;
    const int c   = idx & (NC - 1); idx >>= 3;
    const int dir = idx;                // 0 fwd, 1 bwd

    const float lam = lams.v[c];
    const float* W    = (dir ? Wb : Wf) + c * ND * ND;
    const float* bias = (dir ? bb : bf) + c * ND;
    const float* xb   = x + (size_t)(c * NB + b) * NT * ND;
    float* ob = out + (size_t)dir * (size_t)(NC*NB*NT*ND)
                    + (size_t)(c * NB + b) * NT * ND;

    const int er = lane & 15;   // row/col within 16-tile
    const int ks = lane >> 4;   // k-segment 0..3 (8 elements each)

    // B fragments: B = W^T (K=d, N=e). Lane holds B[k][col=er] with
    // k = ks*8 + j  -> contiguous 8 f32 of W row (e0+er).
    short8 bfrag[4][2];
    #pragma unroll
    for (int et = 0; et < 4; ++et) {
        const float* wr = W + (et*16 + er) * ND + ks * 8;
        #pragma unroll
        for (int kk = 0; kk < 2; ++kk) {
            f32x4 lo = *reinterpret_cast<const f32x4*>(wr + kk*32);
            f32x4 hi = *reinterpret_cast<const f32x4*>(wr + kk*32 + 4);
            bfrag[et][kk] = cvt8(lo, hi);
        }
    }
    float bias_r[4];
    #pragma unroll
    for (int et = 0; et < 4; ++et) bias_r[et] = bias[et*16 + er];

    const int tr0 = k * CL;

    // gated compute: wave w owns t-tiles {2w, 2w+1} = rows [32w, 32w+32)
    #pragma unroll
    for (int u = 0; u < 2; ++u) {
        const int tt   = 2*w + u;
        const int trow = tr0 + tt*16;
        short8 afrag[2];
        {
            const int tg = dir ? (NT-1 - (trow + er)) : (trow + er);
            const float* xr = xb + (size_t)tg * ND + ks * 8;
            #pragma unroll
            for (int kk = 0; kk < 2; ++kk) {
                f32x4 lo = *reinterpret_cast<const f32x4*>(xr + kk*32);
                f32x4 hi = *reinterpret_cast<const f32x4*>(xr + kk*32 + 4);
                afrag[kk] = cvt8(lo, hi);
            }
        }
        #pragma unroll
        for (int et = 0; et < 4; ++et) {
            f32x4 acc = {0.f, 0.f, 0.f, 0.f};
            acc = __builtin_amdgcn_mfma_f32_16x16x32_bf16(afrag[0], bfrag[et][0], acc, 0,0,0);
            acc = __builtin_amdgcn_mfma_f32_16x16x32_bf16(afrag[1], bfrag[et][1], acc, 0,0,0);
            const int col = et*16 + er;
            #pragma unroll
            for (int r = 0; r < 4; ++r) {
                const int row = ks*4 + r;   // C/D: col=lane&15, row=(lane>>4)*4+r
                const int tg  = dir ? (NT-1 - (trow + row)) : (trow + row);
                float z = acc[r] + bias_r[et];
                float g = 1.0f / (1.0f + __expf(-z));
                float xv = xb[(size_t)tg * ND + col];
                buf[tt*16 + row][col] = g * xv;
            }
        }
    }
    // no barrier needed: wave w wrote exactly the rows it scans next

    float lam32 = lam*lam; lam32*=lam32; lam32*=lam32; lam32*=lam32; lam32*=lam32;

    // wave-local sequential scan over rows [32w, 32w+32), lane = d
    float h = 0.f;
    const int r0 = w * 32;
    #pragma unroll 8
    for (int i = 0; i < 32; ++i) {
        float v = buf[r0 + i][lane];
        h = fmaf(h, lam, v);
        buf[r0 + i][lane] = h;
    }
    ends_lds[w][lane] = h;
    __syncthreads();

    // carry into this wave's sub-chunk: Horner over preceding wave ends
    float carry = 0.f;
    for (int j = 0; j < w; ++j) carry = fmaf(carry, lam32, ends_lds[j][lane]);

    // correction + writeback of local (block-level) scan
    float f = lam;
    #pragma unroll 8
    for (int i = 0; i < 32; ++i) {
        const int tr = tr0 + r0 + i;
        const int tg = dir ? (NT-1 - tr) : tr;
        float hv = fmaf(f, carry, buf[r0 + i][lane]);
        ob[(size_t)tg * ND + lane] = hv;
        f *= lam;
    }

    // chunk end (inclusive over whole block) from wave 3
    if (w == 3) {
        float P3 = fmaf(carry, lam32, h);
        ws[(size_t)(((dir*NC + c)*NB + b)*NK + k) * ND + lane] = P3;
    }
}

// K2: cross-chunk carry. Each block recomputes its own carry by Horner
// over all preceding chunk-ends (<=63 cached 256B vectors), then
// out[tr] += lam^{i+1} * carry for its chunk.
__global__ __launch_bounds__(256) void k2_carry(
    float* __restrict__ out, const float* __restrict__ ws, Lams lams)
{
    const int tid  = threadIdx.x;
    const int lane = tid & 63;
    const int w    = tid >> 6;
    int idx = blockIdx.x;
    const int k   = idx & (NK - 1); idx >>= 6;
    const int b   = idx & (NB - 1); idx >>= 2;
    const int c   = idx & (NC - 1); idx >>= 3;
    const int dir = idx;
    if (c == 0 || k == 0) return;   // lam=0 or first chunk: carry is zero

    const float lam = lams.v[c];
    float lamL = lam;
    #pragma unroll
    for (int j = 0; j < 7; ++j) lamL *= lamL;   // lam^128

    const float* wsb = ws + (size_t)(((dir*NC + c)*NB + b)*NK) * ND;
    float P = 0.f;
    for (int j = 0; j < k; ++j) P = fmaf(P, lamL, wsb[(size_t)j * ND + lane]);

    float lam32 = lam*lam; lam32*=lam32; lam32*=lam32; lam32*=lam32; lam32*=lam32;
    float f = lam;
    for (int j = 0; j < w; ++j) f *= lam32;     // lam^{32w+1}

    float* ob = out + (size_t)dir * (size_t)(NC*NB*NT*ND)
                    + (size_t)(c * NB + b) * NT * ND;
    const int tr0 = k*CL + w*32;
    #pragma unroll 4
    for (int i = 0; i < 32; ++i) {
        const int tr = tr0 + i;
        const int tg = dir ? (NT-1 - tr) : tr;
        float* p = ob + (size_t)tg * ND + lane;
        *p = fmaf(f, P, *p);
        f *= lam;
    }
}

extern "C" void kernel_launch(void* const* d_in, const int* in_sizes, int n_in,
                              void* d_out, int out_size, void* d_ws, size_t ws_size,
                              hipStream_t stream)
{
    const float* x  = (const float*)d_in[0];
    const float* Wf = (const float*)d_in[1];
    const float* bf = (const float*)d_in[2];
    const float* Wb = (const float*)d_in[3];
    const float* bb = (const float*)d_in[4];
    float* out = (float*)d_out;
    float* ws  = (float*)d_ws;   // needs 2*8*4*64*64*4 = 512 KiB

    Lams lams;
    const double delta = 13.0 / 7.0;   // log2(8192)/(C-1)
    for (int c = 0; c < 8; ++c)
        lams.v[c] = (float)(1.0 - pow(2.0, -(double)c * delta));

    dim3 grid(2 * NC * NB * NK);   // 4096 blocks
    k1_local<<<grid, 256, 0, stream>>>(x, Wf, bf, Wb, bb, out, ws, lams);
    k2_carry<<<grid, 256, 0, stream>>>(out, ws, lams);
}